// Round 2
// baseline (3489.967 us; speedup 1.0000x reference)
//
#include <hip/hip_runtime.h>
#include <stdint.h>

// ---------------------------------------------------------------------------
// StageNet forward on MI355X — ROUND 13 (R12 resubmit; prior bench was an
// infra failure: container died twice before any dispatch ran).
// R11: 1706us = k_gemm_xk 569us + 50x k_step ~1075us + prep/final.
// This round: batch-independent scan -> ONE persistent kernel
// (k_scan, grid 16 blocks x 512 thr, 16 b-rows/block, no grid sync):
//   per step: h@Wr^T via MFMA 16x16x32 (Wr L2-resident, A=h in LDS bf16),
//   xout kept in LDS (stride 1668, 2-way banks), gates computed ONCE,
//   c state in registers, only hbuf/dbuf written to global.
// k_final simplified (no step-49 gates; reads hbuf/dbuf only).
// Predicted: k_scan ~350-500us (per-CU L2 BW on Wr 1.28MB/step), total ~1.0-1.15ms.
// ---------------------------------------------------------------------------

typedef unsigned short u16;
typedef short bf16x8 __attribute__((ext_vector_type(8)));
typedef float f32x4 __attribute__((ext_vector_type(4)));

#define GLL(gp, lp)                                                            \
  __builtin_amdgcn_global_load_lds(                                            \
      (const __attribute__((address_space(1))) unsigned int*)(gp),             \
      (__attribute__((address_space(3))) unsigned int*)(lp), 16, 0, 0)

__device__ __forceinline__ float bf2f(u16 u) {
  union { unsigned int i; float f; } v;
  v.i = ((unsigned int)u) << 16;
  return v.f;
}
__device__ __forceinline__ u16 f2bf(float f) {
  union { float f; unsigned int i; } v;
  v.f = f;
  unsigned int r = (v.i + 0x7fffu + ((v.i >> 16) & 1u)) >> 16;
  return (u16)r;
}
__device__ __forceinline__ float ldf(const void* p, size_t i, int isbf) {
  return isbf ? bf2f(((const u16*)p)[i]) : ((const float*)p)[i];
}
__device__ __forceinline__ float sigf(float x) { return 1.f / (1.f + __expf(-x)); }
__device__ __forceinline__ float tanhf_(float x) {
  float cx = fminf(fmaxf(x, -15.f), 15.f);
  float e = __expf(2.f * cx);
  return (e - 1.f) / (e + 1.f);
}
__device__ __forceinline__ float dot8_bf(const u16* w, const float* lp) {
  uint4 wv = *(const uint4*)w;
  union { unsigned int u; float f; } a0, a1;
  float s;
  a0.u = wv.x << 16; a1.u = wv.x & 0xffff0000u;
  s = lp[0] * a0.f + lp[1] * a1.f;
  a0.u = wv.y << 16; a1.u = wv.y & 0xffff0000u;
  s += lp[2] * a0.f + lp[3] * a1.f;
  a0.u = wv.z << 16; a1.u = wv.z & 0xffff0000u;
  s += lp[4] * a0.f + lp[5] * a1.f;
  a0.u = wv.w << 16; a1.u = wv.w & 0xffff0000u;
  s += lp[6] * a0.f + lp[7] * a1.f;
  return s;
}

// ------------------------- dtype detection (safety) ------------------------
__global__ void k_detect(const unsigned int* __restrict__ emb_raw,
                         int* __restrict__ flag) {
  if (blockIdx.x == 0 && threadIdx.x == 0) {
    int cnt = 0;
    for (int i = 64; i < 128; ++i) {
      unsigned int u = emb_raw[i];
      unsigned int lo = u & 0xffffu;
      unsigned int ex = (lo >> 7) & 0xffu;
      if (lo != 0 && ex >= 100 && ex <= 126) ++cnt;
    }
    *flag = (cnt >= 32) ? 1 : 0;
  }
}

// ------------------------- canonicalization --------------------------------
__global__ void k_cvt_emb(const void* __restrict__ src, u16* __restrict__ dst,
                          const int* __restrict__ flagp) {
  int isbf = *flagp;
  int n = 10001 * 128;
  int i = blockIdx.x * blockDim.x + threadIdx.x;
  int stride = gridDim.x * blockDim.x;
  for (; i < n; i += stride)
    dst[i] = isbf ? ((const u16*)src)[i] : f2bf(((const float*)src)[i]);
}

__global__ void k_repack_wk(const void* __restrict__ wk, u16* __restrict__ wkp,
                            const int* __restrict__ flagp) {
  int isbf = *flagp;
  size_t i = (size_t)blockIdx.x * blockDim.x + threadIdx.x;
  size_t total = (size_t)1664 * 8192;
  size_t stride = (size_t)gridDim.x * blockDim.x;
  for (; i < total; i += stride) {
    size_t g = i >> 13, k = i & 8191;
    wkp[i] = (g < 1552) ? f2bf(ldf(wk, g * 8193 + k, isbf)) : (u16)0;
  }
}

// wrBf[g][k] bf16, g padded to 1664 (zeros); + biasC, wlC
__global__ void k_prep_wr(const void* __restrict__ wr, const void* __restrict__ wk,
                          const void* __restrict__ bk, const void* __restrict__ br,
                          u16* __restrict__ wrBf, float* __restrict__ biasC,
                          float* __restrict__ wlC, const int* __restrict__ flagp) {
  int isbf = *flagp;
  int i0 = blockIdx.x * blockDim.x + threadIdx.x;
  int stride = gridDim.x * blockDim.x;
  for (int j = i0; j < 1664 * 384; j += stride) {
    int g = j / 384, k = j - g * 384;
    wrBf[j] = (g < 1552) ? f2bf(ldf(wr, (size_t)g * 385 + k, isbf)) : (u16)0;
  }
  for (int g = i0; g < 1552; g += stride) {
    biasC[g] = ldf(bk, g, isbf) + ldf(br, g, isbf);
    wlC[g] = ldf(wk, (size_t)g * 8193 + 8192, isbf) + ldf(wr, g * 385 + 384, isbf);
  }
}

__global__ void k_repack_wc(const void* __restrict__ wc, u16* __restrict__ wcp,
                            const int* __restrict__ flagp) {
  int isbf = *flagp;
  int i0 = blockIdx.x * blockDim.x + threadIdx.x;
  int stride = gridDim.x * blockDim.x;
  for (int j = i0; j < 384 * 3840; j += stride) {
    int o = j / 3840;
    int r = j - o * 3840;
    int k = r / 384;
    int h = r - k * 384;
    wcp[j] = f2bf(ldf(wc, (o * 384 + h) * 10 + k, isbf));  // [o][h][k]->[o][k][h]
  }
}

// canonical fp32: [vt 12800][Ws 24576][bs 64][Wrs 24576][brs 384][bc 384]
//                 [Wo 49152][bo 128]  (total 112064 floats)
__global__ void k_cvt_smalls(const void* vt, const void* Ws, const void* bs,
                             const void* Wrs, const void* brs, const void* bc,
                             const void* Wo, const void* bo,
                             float* __restrict__ dst, const int* __restrict__ flagp) {
  int isbf = *flagp;
  int i = blockIdx.x * blockDim.x + threadIdx.x;
  int stride = gridDim.x * blockDim.x;
  for (; i < 112064; i += stride) {
    float v;
    if (i < 12800) v = ldf(vt, i, isbf);
    else if (i < 37376) v = ldf(Ws, i - 12800, isbf);
    else if (i < 37440) v = ldf(bs, i - 37376, isbf);
    else if (i < 62016) v = ldf(Wrs, i - 37440, isbf);
    else if (i < 62400) v = ldf(brs, i - 62016, isbf);
    else if (i < 62784) v = ldf(bc, i - 62400, isbf);
    else if (i < 111936) v = ldf(Wo, i - 62784, isbf);
    else v = ldf(bo, i - 111936, isbf);
    dst[i] = v;
  }
}

// ------------------------- PH1: gathered GEMM, swizzled GLL staging --------
// grid (13 g-tiles, 100 m-tiles), 256 threads. Tile 128x128, BK=64 bf16.
__global__ __launch_bounds__(256) void k_gemm_xk(
    const int* __restrict__ node_ids, const u16* __restrict__ embB,
    const u16* __restrict__ wkp, const float* __restrict__ vtF,
    const float* __restrict__ biasC, const float* __restrict__ wlC,
    u16* __restrict__ xkb) {
  __shared__ alignas(16) u16 As[128 * 64];
  __shared__ alignas(16) u16 Bs[128 * 64];
  int tid = threadIdx.x;
  int m0 = blockIdx.y * 128;
  int g0 = blockIdx.x * 128;
  int lane = tid & 63, w = tid >> 6;
  int wy = w >> 1, wx = w & 1;
  f32x4 acc[4][4];
#pragma unroll
  for (int i = 0; i < 4; ++i)
#pragma unroll
    for (int j = 0; j < 4; ++j) acc[i][j] = (f32x4){0.f, 0.f, 0.f, 0.f};

  int l15 = lane & 15, lq = lane >> 4;
  int lr = lane >> 3, lc = lane & 7;  // row-in-chunk, 16B-chunk slot
  int swc = (lc ^ lr) * 8;            // swizzled global chunk offset (u16)
  int cRd = (lq ^ (l15 & 7)) * 8;     // swizzled read chunk, ks=0 (u16)

  for (int kt = 0; kt < 128; ++kt) {
    __syncthreads();
    // ---- stage A (gathered embed rows), swizzled global chunk
#pragma unroll
    for (int c = 0; c < 4; ++c) {
      int chunk = w * 4 + c;
      int r = chunk * 8 + lr;
      int id = node_ids[(size_t)(m0 + r) * 64 + (kt >> 1)];
      const u16* gp = embB + (size_t)id * 128 + (kt & 1) * 64 + swc;
      u16* lp = As + chunk * 512 + lane * 8;
      GLL(gp, lp);
    }
    // ---- stage B (Wk tile), swizzled global chunk
#pragma unroll
    for (int c = 0; c < 4; ++c) {
      int chunk = w * 4 + c;
      int r = chunk * 8 + lr;
      const u16* gp = wkp + (size_t)(g0 + r) * 8192 + (size_t)kt * 64 + swc;
      u16* lp = Bs + chunk * 512 + lane * 8;
      GLL(gp, lp);
    }
    __syncthreads();
    const u16* Ab = As + (wy * 64 + l15) * 64;
    const u16* Bb = Bs + (wx * 64 + l15) * 64;
#pragma unroll
    for (int ks = 0; ks < 2; ++ks) {
      int co = cRd ^ (ks * 32);
      bf16x8 av[4], bv[4];
#pragma unroll
      for (int i = 0; i < 4; ++i) av[i] = *(const bf16x8*)(Ab + i * 1024 + co);
#pragma unroll
      for (int j = 0; j < 4; ++j) bv[j] = *(const bf16x8*)(Bb + j * 1024 + co);
#pragma unroll
      for (int i = 0; i < 4; ++i)
#pragma unroll
        for (int j = 0; j < 4; ++j)
          acc[i][j] =
              __builtin_amdgcn_mfma_f32_16x16x32_bf16(av[i], bv[j], acc[i][j], 0, 0, 0);
    }
  }
  float vt[4][4];
#pragma unroll
  for (int i = 0; i < 4; ++i)
#pragma unroll
    for (int p = 0; p < 4; ++p)
      vt[i][p] = vtF[m0 + wy * 64 + i * 16 + lq * 4 + p];
#pragma unroll
  for (int j = 0; j < 4; ++j) {
    int gcol = g0 + wx * 64 + j * 16 + l15;
    if (gcol < 1552) {
      float bC = biasC[gcol], wC = wlC[gcol];
#pragma unroll
      for (int i = 0; i < 4; ++i)
#pragma unroll
        for (int p = 0; p < 4; ++p) {
          int grow = m0 + wy * 64 + i * 16 + lq * 4 + p;
          xkb[(size_t)grow * 1552 + gcol] = f2bf(acc[i][j][p] + bC + vt[i][p] * wC);
        }
    }
  }
}

// ------------------------- PH2: persistent 50-step scan --------------------
// The recurrence is independent across batch: grid 16 blocks (16 b-rows each),
// 512 threads (8 waves), NO grid sync. Per step:
//   GEMM: xout = h_{t-1} @ Wr^T via MFMA 16x16x32 bf16; A = hS (LDS bf16,
//         stride 392 u16), B = WrBf from global (L2-resident, 1.28MB/step),
//         D -> xoutS (LDS fp32, stride 1668 -> 2-way banks).
//   softmax (lanes 0..31): fm/im cumax over xout[0..16)+XK; dist -> dbuf.
//   gates (all 512): 12 elems/thread, c state in registers, h -> hS bf16
//         (A for next step) + hbuf fp32 (for k_final). XK added at read.
__global__ __launch_bounds__(512, 2) void k_scan(
    const u16* __restrict__ xkb, const u16* __restrict__ wrBf,
    float* __restrict__ hbuf, float* __restrict__ dbuf) {
  __shared__ alignas(16) float xoutS[16 * 1668];  // 106752 B
  __shared__ alignas(16) u16 hS[16][392];         // 12544 B
  __shared__ float fmS[16][8], imS[16][8];
  int tid = threadIdx.x;
  int b0 = blockIdx.x * 16;
  int wv = tid >> 6, lane = tid & 63, l15 = lane & 15, lq = lane >> 4;
  int g0w = wv * 208;  // 8 waves x 13 tiles of 16 = 1664 (Wr zero-padded)

  float creg[12];
#pragma unroll
  for (int k = 0; k < 12; ++k) creg[k] = 0.f;
  for (int i = tid; i < 16 * 392; i += 512) ((u16*)hS)[i] = 0;
  __syncthreads();

  const u16* arow = &hS[l15][0] + lq * 8;
  const u16* bbase = wrBf + (size_t)(g0w + l15) * 384 + lq * 8;

  for (int t = 0; t < 50; ++t) {
    // ---- GEMM phase: xoutS[b][g] = (h_{t-1} @ Wr^T)[b][g]
    bf16x8 af[12];
#pragma unroll
    for (int ks = 0; ks < 12; ++ks)
      af[ks] = *(const bf16x8*)(arow + ks * 32);
#pragma unroll 2
    for (int gt = 0; gt < 13; ++gt) {
      const u16* bp = bbase + gt * (16 * 384);
      f32x4 acc = (f32x4){0.f, 0.f, 0.f, 0.f};
#pragma unroll
      for (int ks = 0; ks < 12; ++ks) {
        bf16x8 bv = *(const bf16x8*)(bp + ks * 32);
        acc = __builtin_amdgcn_mfma_f32_16x16x32_bf16(af[ks], bv, acc, 0, 0, 0);
      }
      int gb = g0w + gt * 16 + l15;
#pragma unroll
      for (int p = 0; p < 4; ++p) xoutS[(lq * 4 + p) * 1668 + gb] = acc[p];
    }
    __syncthreads();

    // ---- softmax phase (fm: lanes 0..15, im: lanes 16..31)
    if (tid < 32) {
      int r = tid & 15;
      const float* xr = xoutS + r * 1668;
      const u16* xkr = xkb + ((size_t)(b0 + r) * 50 + t) * 1552;
      if (tid < 16) {
        float z[8];
        float m = -1e30f;
#pragma unroll
        for (int j = 0; j < 8; ++j) { z[j] = xr[j] + bf2f(xkr[j]); m = fmaxf(m, z[j]); }
        float s = 0.f;
#pragma unroll
        for (int j = 0; j < 8; ++j) { z[j] = __expf(z[j] - m); s += z[j]; }
        float inv = 1.f / s, run = 0.f, fsum = 0.f;
#pragma unroll
        for (int j = 0; j < 8; ++j) { run += z[j] * inv; fmS[r][j] = run; fsum += run; }
        dbuf[(size_t)t * 256 + (b0 + r)] = 1.f - fsum * 0.125f;
      } else {
        float z[8];
        float m = -1e30f;
#pragma unroll
        for (int j = 0; j < 8; ++j) { z[j] = xr[8 + j] + bf2f(xkr[8 + j]); m = fmaxf(m, z[j]); }
        float s = 0.f;
#pragma unroll
        for (int j = 0; j < 8; ++j) { z[j] = __expf(z[j] - m); s += z[j]; }
        float inv = 1.f / s, run = 0.f;
#pragma unroll
        for (int j = 7; j >= 0; --j) { run += z[j] * inv; imS[r][j] = run; }
      }
    }
    __syncthreads();

    // ---- gate phase: 12 elements per thread (e = k*512 + tid)
#pragma unroll
    for (int k = 0; k < 12; ++k) {
      int e = k * 512 + tid;
      int bl = e / 384;
      int h = e - bl * 384;
      const float* xg = xoutS + bl * 1668 + 16;
      const u16* xkg = xkb + ((size_t)(b0 + bl) * 50 + t) * 1552 + 16;
      float fg = sigf(xg[h] + bf2f(xkg[h]));
      float ig = sigf(xg[h + 384] + bf2f(xkg[h + 384]));
      float og = sigf(xg[h + 768] + bf2f(xkg[h + 768]));
      float ci = tanhf_(xg[h + 1152] + bf2f(xkg[h + 1152]));
      int l = h / 48;
      float fm = fmS[bl][l], im = imS[bl][l];
      float ov = fm * im;
      float cl = creg[k];
      float cn = ov * (fg * cl + ig * ci) + (fm - ov) * cl + (im - ov) * ci;
      float hn = og * tanhf_(cn);
      creg[k] = cn;
      hbuf[((size_t)t * 256 + (b0 + bl)) * 384 + h] = hn;
      hS[bl][h] = f2bf(hn);
    }
    __syncthreads();
  }
}

// ------------------------- PH3: final (theme/conv/out; no gates) -----------
__global__ __launch_bounds__(384) void k_final(
    const float* __restrict__ hbuf, const float* __restrict__ dbuf,
    const unsigned char* __restrict__ am, const float* __restrict__ smalls,
    const u16* __restrict__ wcp, float* __restrict__ out) {
  const float* WsF = smalls + 12800;
  const float* bsF = smalls + 37376;
  const float* WrsF = smalls + 37440;
  const float* brsF = smalls + 62016;
  const float* bcF = smalls + 62400;
  const float* WoF = smalls + 62784;
  const float* boF = smalls + 111936;
  __shared__ alignas(16) float lh2[10][384];
  __shared__ alignas(16) float ti[384];
  __shared__ alignas(16) float us[64];
  __shared__ alignas(16) float rnnS[384];
  __shared__ alignas(16) float hlastS[384];
  __shared__ float ldS[10];
  __shared__ int npad[50];
  __shared__ int lastS;
  int tid = threadIdx.x;
  int b = blockIdx.x;

  if (tid < 50) {
    const unsigned char* mr = am + ((size_t)b * 50 + tid) * 64;
    int all1 = 1;
    for (int q = 0; q < 64; ++q) all1 &= (mr[q] != 0);
    npad[tid] = all1 ? 0 : 1;
  }
  __syncthreads();
  if (tid == 0) {
    int c = 0;
    for (int v = 0; v < 50; ++v) c += npad[v];
    int lv = c - 1;
    int last = lv < 0 ? 0 : lv;
    lastS = last;
    float cum = 0.f, cv[10];
    for (int k = 0; k < 10; ++k) {
      int s = last - 9 + k;
      float dk = (s >= 0) ? dbuf[(size_t)s * 256 + b] : 0.f;
      cum += dk;
      cv[k] = cum;
    }
    float m = cv[0];
    for (int k = 1; k < 10; ++k) m = fmaxf(m, cv[k]);
    float ssum = 0.f, ee[10];
    for (int k = 0; k < 10; ++k) { ee[k] = __expf(cv[k] - m); ssum += ee[k]; }
    float inv = 1.f / ssum;
    for (int k = 0; k < 10; ++k) ldS[k] = ee[k] * inv;
  }
  __syncthreads();
  {  // local_h, theme input, h_last
    int h = tid;
    int last = lastS;
    float ssum = 0.f;
    for (int k = 0; k < 10; ++k) {
      int s = last - 9 + k;
      float hv = (s >= 0) ? hbuf[((size_t)s * 256 + b) * 384 + h] : 0.f;
      float v = hv * ldS[k];
      lh2[k][h] = v;
      ssum += v;
    }
    ti[h] = ssum * 0.1f;
    hlastS[h] = hbuf[((size_t)last * 256 + b) * 384 + h];
  }
  __syncthreads();
  if (tid < 64) {  // u = relu(ti @ Ws^T + bs)
    float a = bsF[tid];
    const float* wr = WsF + (size_t)tid * 384;
    for (int h = 0; h < 384; ++h) a += wr[h] * ti[h];
    us[tid] = fmaxf(a, 0.f);
  }
  __syncthreads();
  {  // theme = sigmoid(u @ Wrs^T + brs); conv; rnn = theme*conv + h_last
    int o = tid;
    float th = brsF[o];
    const float* wr = WrsF + (size_t)o * 64;
    for (int k = 0; k < 64; ++k) th += wr[k] * us[k];
    th = sigf(th);
    float cacc = bcF[o];
    for (int k = 0; k < 10; ++k) {
      const u16* wrow = wcp + ((size_t)o * 10 + k) * 384;
      const float* lrow = lh2[k];
      for (int h8 = 0; h8 < 48; ++h8) cacc += dot8_bf(wrow + h8 * 8, lrow + h8 * 8);
    }
    rnnS[o] = th * cacc + hlastS[o];
  }
  __syncthreads();
  if (tid < 128) {  // out = rnn @ Wo^T + bo, fp32
    float a = boF[tid];
    const float* wr = WoF + (size_t)tid * 384;
    for (int h = 0; h < 384; ++h) a += wr[h] * rnnS[h];
    out[(size_t)b * 128 + tid] = a;
  }
}

// ------------------------- launch ------------------------------------------
extern "C" void kernel_launch(void* const* d_in, const int* in_sizes, int n_in,
                              void* d_out, int out_size, void* d_ws, size_t ws_size,
                              hipStream_t stream) {
  const int* node_ids = (const int*)d_in[0];
  const void* vtR = d_in[3];
  const unsigned char* am = (const unsigned char*)d_in[5];
  const void* embR = d_in[6];
  const void* WkR = d_in[7];
  const void* bkR = d_in[8];
  const void* WrR = d_in[9];
  const void* brR = d_in[10];
  const void* WsR = d_in[11];
  const void* bsR = d_in[12];
  const void* WrsR = d_in[13];
  const void* brsR = d_in[14];
  const void* WcR = d_in[15];
  const void* bcR = d_in[16];
  const void* WoR = d_in[17];
  const void* boR = d_in[18];
  (void)in_sizes; (void)n_in; (void)out_size; (void)ws_size;

  char* ws = (char*)d_ws;
  size_t off = 0;
  auto alloc = [&](size_t bytes) {
    void* p = ws + off;
    off = (off + bytes + 255) & ~(size_t)255;
    return p;
  };
  int* flagp = (int*)alloc(4);
  u16* embB = (u16*)alloc((size_t)10001 * 128 * 2);      // 2.56MB
  u16* WkP = (u16*)alloc((size_t)1664 * 8192 * 2);       // 27.3MB
  u16* WrBf = (u16*)alloc((size_t)1664 * 384 * 2);       // 1.28MB bf16 [g][k]
  float* biasC = (float*)alloc(1552 * 4);
  float* wlC = (float*)alloc(1552 * 4);
  float* smalls = (float*)alloc((size_t)112064 * 4);
  u16* XKb = (u16*)alloc((size_t)12800 * 1552 * 2);      // 39.7MB
  u16* WcP = (u16*)alloc((size_t)384 * 3840 * 2);        // 2.9MB
  float* Hbuf = (float*)alloc((size_t)50 * 256 * 384 * 4);  // 19.7MB
  float* Dbuf = (float*)alloc((size_t)50 * 256 * 4);

  k_detect<<<dim3(1), dim3(64), 0, stream>>>((const unsigned int*)embR, flagp);
  k_cvt_emb<<<dim3(1024), dim3(256), 0, stream>>>(embR, embB, flagp);
  k_repack_wk<<<dim3(2048), dim3(256), 0, stream>>>(WkR, WkP, flagp);
  k_prep_wr<<<dim3(512), dim3(256), 0, stream>>>(WrR, WkR, bkR, brR, WrBf, biasC,
                                                 wlC, flagp);
  k_repack_wc<<<dim3(512), dim3(256), 0, stream>>>(WcR, WcP, flagp);
  k_cvt_smalls<<<dim3(128), dim3(256), 0, stream>>>(vtR, WsR, bsR, WrsR, brsR,
                                                    bcR, WoR, boR, smalls, flagp);

  k_gemm_xk<<<dim3(13, 100), dim3(256), 0, stream>>>(node_ids, embB, WkP, smalls,
                                                     biasC, wlC, XKb);

  k_scan<<<dim3(16), dim3(512), 0, stream>>>(XKb, WrBf, Hbuf, Dbuf);

  k_final<<<dim3(256), dim3(384), 0, stream>>>(Hbuf, Dbuf, am, smalls, WcP,
                                               (float*)d_out);
}